// Round 3
// baseline (303.826 us; speedup 1.0000x reference)
//
#include <hip/hip_runtime.h>
#include <math.h>

#define NB 64
#define NA 8732
#define NC 81
#define TOTAL (NB * NA)    /* 558848 */
#define APB 64             /* anchors per block */
#define TPB 256            /* threads per block: 4 threads per anchor */
#define NBLK (TOTAL / APB) /* 8732 */

// ws layout (no init kernel: every word read is stored in-iteration;
// 'done' is zeroed by main_kernel block 0 before topk runs):
//   float conf_neg[TOTAL]
//   int   pos_count[NB]    (written by topk_kernel)
//   float accv[NB]         (per-image neg-topk sum, written by topk_kernel)
//   float block_loc[NBLK]
//   float block_pcs[NBLK]
//   int   done             (last-topk-block detection counter)

// quad_perm butterfly all-reduce within each 4-lane group (full-rate VALU)
__device__ __forceinline__ float quadsum(float x) {
    x += __int_as_float(__builtin_amdgcn_update_dpp(
        0, __float_as_int(x), 0xB1, 0xF, 0xF, true));   // [1,0,3,2]
    x += __int_as_float(__builtin_amdgcn_update_dpp(
        0, __float_as_int(x), 0x4E, 0xF, 0xF, true));   // [2,3,0,1]
    return x;
}

// async global->LDS, 16B per lane. LDS dest is wave-uniform base + lane*16;
// our layout is exactly linear (dst[tid] = src[tid]) so this is valid.
__device__ __forceinline__ void gload_lds16(const float4* g, float4* l) {
    __builtin_amdgcn_global_load_lds(
        (const __attribute__((address_space(1))) unsigned int*)g,
        (__attribute__((address_space(3))) unsigned int*)l,
        16, 0, 0);
}

// Bulk-staged softmax CE. APB=64 -> 21 KB LDS -> 7 blocks/CU, so each
// block's vmcnt(0) barrier drain hides under 6 other resident blocks.
__global__ __launch_bounds__(TPB, 7) void main_kernel(
    const float* __restrict__ scores, const float* __restrict__ boxes,
    const int* __restrict__ gt_labels, const float* __restrict__ gt_boxes,
    const int* __restrict__ mask, float* __restrict__ conf_neg,
    float* __restrict__ block_loc, float* __restrict__ block_pcs,
    int* __restrict__ done)
{
    __shared__ float lds[APB * NC + 256];   // 5184 + pad (partial-wave safety)
    __shared__ float wredl[4], wredp[4];
    const int tid  = threadIdx.x;
    const int lane = tid & 63;
    const int wid  = tid >> 6;        // 4 waves
    const int base = blockIdx.x * APB;

    if (blockIdx.x == 0 && tid == 0) *done = 0;   // for topk's last-block sync

    // ---- staging: 1296 float4 = 5*256 + 16, direct-to-LDS ----
    const float4* __restrict__ src = (const float4*)(scores + (size_t)base * NC);
    float4* dst = (float4*)lds;
    gload_lds16(src + tid,        dst + tid);
    gload_lds16(src + tid +  256, dst + tid +  256);
    gload_lds16(src + tid +  512, dst + tid +  512);
    gload_lds16(src + tid +  768, dst + tid +  768);
    gload_lds16(src + tid + 1024, dst + tid + 1024);
    if (tid < 16) gload_lds16(src + tid + 1280, dst + tid + 1280);

    // ---- loc part (overlaps staging): threads 0..63 own one anchor ----
    float loc = 0.0f;
    if (tid < APB) {
        const int a = base + tid;
        if (mask[a]) {
            const float4 bx = *(const float4*)(boxes    + (size_t)a * 4);
            const float4 gb = *(const float4*)(gt_boxes + (size_t)a * 4);
            const float d0 = bx.x - gb.x, d1 = bx.y - gb.y;
            const float d2 = bx.z - gb.z, d3 = bx.w - gb.w;
            const float a0 = fabsf(d0), a1 = fabsf(d1), a2 = fabsf(d2), a3 = fabsf(d3);
            loc = (a0 < 1.f ? 0.5f * d0 * d0 : a0 - 0.5f)
                + (a1 < 1.f ? 0.5f * d1 * d1 : a1 - 0.5f)
                + (a2 < 1.f ? 0.5f * d2 * d2 : a2 - 0.5f)
                + (a3 < 1.f ? 0.5f * d3 * d3 : a3 - 0.5f);
        }
    }
    __syncthreads();                  // drains global_load_lds (vmcnt 0)

    // ---- CE: 4 threads per anchor, 20(+1) classes each ----
    const int al = tid >> 2;          // local anchor 0..63
    const int q  = tid & 3;
    const float* __restrict__ row = lds + al * NC;
    float e = 0.0f;
    #pragma unroll
    for (int j = 0; j < 20; ++j) e += __expf(row[q * 20 + j]);
    if (q == 3) e += __expf(row[80]);
    e = quadsum(e);                   // all 4 lanes hold sum(exp)

    float pcs = 0.0f;
    if (q == 0) {                     // leader: 16 lanes/wave, coalesced I/O
        const int a = base + al;
        const int lab = gt_labels[a];
        const float c = __logf(e) - row[lab];
        const int m = mask[a];
        conf_neg[a] = m ? 0.f : c;
        pcs = m ? c : 0.f;
    }

    #pragma unroll
    for (int o = 32; o; o >>= 1) {
        loc += __shfl_down(loc, o);
        pcs += __shfl_down(pcs, o);
    }
    if (lane == 0) { wredl[wid] = loc; wredp[wid] = pcs; }
    __syncthreads();
    if (tid == 0) {
        block_loc[blockIdx.x] = wredl[0] + wredl[1] + wredl[2] + wredl[3];
        block_pcs[blockIdx.x] = wredp[0] + wredp[1] + wredp[2] + wredp[3];
    }
}

// One block per batch row. Computes k = 3*popcount(mask row) (fused into the
// staging loop), exact k-th-largest via radix-256 select on float bits, sum
// of top-k with tie handling. The LAST block to finish (device-scope counter)
// also performs the final global reduction and writes the outputs.
__global__ __launch_bounds__(1024) void topk_kernel(
    const float* __restrict__ conf_neg, const int* __restrict__ mask,
    int* __restrict__ pos_count, float* __restrict__ accv,
    const float* __restrict__ block_loc, const float* __restrict__ block_pcs,
    int* __restrict__ done, float* __restrict__ out)
{
    __shared__ unsigned sv[NA];                     // 34928 B
    __shared__ __align__(16) int whist[64][256];    // 65536 B, per-16-lane-group
    __shared__ int hist4[4][256];                   // 4096 B partial combine
    __shared__ int   redi[16];
    __shared__ float redf[16];
    __shared__ float rl[16], rp[16];
    __shared__ unsigned spfx;
    __shared__ int skr;
    __shared__ int sk;
    __shared__ int lastflag;
    const int tid  = threadIdx.x;
    const int lane = tid & 63;
    const int wid  = tid >> 6;
    const int hid  = tid >> 4;       // 64 sub-histograms
    const int b = blockIdx.x;
    const float* __restrict__ row  = conf_neg + (size_t)b * NA;
    const int*   __restrict__ mrow = mask     + (size_t)b * NA;

    // stage values + count positives in one pass
    int myc = 0;
    for (int i = tid; i < NA; i += 1024) {
        sv[i] = __float_as_uint(row[i]);
        myc += mrow[i];
    }
    #pragma unroll
    for (int o = 32; o; o >>= 1) myc += __shfl_down(myc, o);
    if (lane == 0) redi[wid] = myc;
    __syncthreads();
    if (tid == 0) {
        int p = 0;
        #pragma unroll
        for (int w = 0; w < 16; ++w) p += redi[w];
        pos_count[b] = p;
        int kk = 3 * p;
        if (kk > NA) kk = NA;
        sk = kk;
    }
    __syncthreads();
    const int k = sk;                // block-uniform

    if (k > 0) {
        unsigned prefix = 0u;
        int kr = k;
        for (int shift = 24; shift >= 0; shift -= 8) {
            // clear 64x256 ints with int4 stores: 4 per thread
            int4* w4 = (int4*)whist;
            const int4 z = make_int4(0, 0, 0, 0);
            w4[tid] = z; w4[tid + 1024] = z; w4[tid + 2048] = z; w4[tid + 3072] = z;
            __syncthreads();                                   // A

            const unsigned himask = (shift == 24) ? 0u : (0xFFFFFFFFu << (shift + 8));
            for (int i = tid; i < NA; i += 1024) {
                const unsigned v = sv[i];
                if ((v & himask) == prefix)
                    atomicAdd(&whist[hid][(v >> shift) & 255], 1);
            }
            __syncthreads();                                   // B

            // combine 64 copies -> hist4[4][256]
            {
                const int p = tid >> 8;        // 0..3
                const int bb = tid & 255;
                int s = 0;
                #pragma unroll
                for (int w = 0; w < 16; ++w) s += whist[(p << 4) + w][bb];
                hist4[p][bb] = s;
            }
            __syncthreads();                                   // C

            // wave 0: suffix-count over 256 bins + k-th bin select
            if (wid == 0) {
                int h0, h1, h2, h3;
                {
                    const int b0i = 4 * lane;
                    h0 = hist4[0][b0i]     + hist4[1][b0i]     + hist4[2][b0i]     + hist4[3][b0i];
                    h1 = hist4[0][b0i + 1] + hist4[1][b0i + 1] + hist4[2][b0i + 1] + hist4[3][b0i + 1];
                    h2 = hist4[0][b0i + 2] + hist4[1][b0i + 2] + hist4[2][b0i + 2] + hist4[3][b0i + 2];
                    h3 = hist4[0][b0i + 3] + hist4[1][b0i + 3] + hist4[2][b0i + 3] + hist4[3][b0i + 3];
                }
                const int s3 = h3, s2 = h2 + s3, s1 = h1 + s2, s0 = h0 + s1;
                int incl = s0;
                #pragma unroll
                for (int off = 1; off < 64; off <<= 1) {
                    const int v = __shfl_down(incl, off);
                    if (lane + off < 64) incl += v;
                }
                const int E = incl - s0;       // count in bins > 4*lane+3
                const int S0 = E + s0, S1 = E + s1, S2 = E + s2, S3 = E + s3;
                if (S0 >= kr && S1 < kr) { spfx = prefix | ((unsigned)(4 * lane)     << shift); skr = kr - S1; }
                else if (S1 >= kr && S2 < kr) { spfx = prefix | ((unsigned)(4 * lane + 1) << shift); skr = kr - S2; }
                else if (S2 >= kr && S3 < kr) { spfx = prefix | ((unsigned)(4 * lane + 2) << shift); skr = kr - S3; }
                else if (S3 >= kr && E  < kr) { spfx = prefix | ((unsigned)(4 * lane + 3) << shift); skr = kr - E;  }
            }
            __syncthreads();                                   // D (publish)
            prefix = spfx;
            kr = skr;
        }

        // prefix == bits of the k-th largest value T.
        // sum = sum(v > T) + (k - count(v > T)) * T   (exact tie handling)
        float s = 0.0f; int cg = 0;
        for (int i = tid; i < NA; i += 1024) {
            const unsigned u = sv[i];
            if (u > prefix) { s += __uint_as_float(u); cg++; }
        }
        #pragma unroll
        for (int o = 32; o; o >>= 1) { s += __shfl_down(s, o); cg += __shfl_down(cg, o); }
        if ((tid & 63) == 0) { redf[wid] = s; redi[wid] = cg; }
        __syncthreads();
        if (tid == 0) {
            float ts = 0.f; int tc = 0;
            #pragma unroll
            for (int w = 0; w < 16; ++w) { ts += redf[w]; tc += redi[w]; }
            ts += (float)(k - tc) * __uint_as_float(prefix);
            accv[b] = ts;
        }
    } else {
        if (tid == 0) accv[b] = 0.0f;
    }

    // ---- last-block-done: the final global reduction (replaces final_kernel)
    __threadfence();                              // release our stores
    if (tid == 0) lastflag = (atomicAdd(done, 1) == NB - 1);
    __syncthreads();
    if (!lastflag) return;
    __threadfence();                              // acquire others' stores

    float sl = 0.f, sp = 0.f;
    for (int i = tid; i < NBLK; i += 1024) { sl += block_loc[i]; sp += block_pcs[i]; }
    int   p2 = (tid < NB) ? pos_count[tid] : 0;   // wave 0 only
    float sa = (tid < NB) ? accv[tid]      : 0.f; // wave 0 only
    #pragma unroll
    for (int o = 32; o; o >>= 1) {
        sl += __shfl_down(sl, o);
        sp += __shfl_down(sp, o);
        p2 += __shfl_down(p2, o);
        sa += __shfl_down(sa, o);
    }
    if (lane == 0) { rl[wid] = sl; rp[wid] = sp; }
    __syncthreads();
    if (tid == 0) {
        float tl = 0.f, tp = 0.f;
        #pragma unroll
        for (int w = 0; w < 16; ++w) { tl += rl[w]; tp += rp[w]; }
        const float N = fmaxf(1.0f, (float)p2);   // p2, sa live in wave-0 lane-0
        const float loc  = tl / N;
        const float conf = (tp + sa) / N;
        out[0] = loc + conf;
        out[1] = loc;
        out[2] = conf;
    }
}

extern "C" void kernel_launch(void* const* d_in, const int* in_sizes, int n_in,
                              void* d_out, int out_size, void* d_ws, size_t ws_size,
                              hipStream_t stream) {
    const float* scores    = (const float*)d_in[0];
    const float* boxes     = (const float*)d_in[1];
    const int*   gt_labels = (const int*)d_in[2];
    const float* gt_boxes  = (const float*)d_in[3];
    const int*   mask      = (const int*)d_in[4];
    float* out = (float*)d_out;

    float* conf_neg  = (float*)d_ws;
    int*   pos_count = (int*)(conf_neg + TOTAL);
    float* accv      = (float*)(pos_count + NB);
    float* block_loc = accv + NB;
    float* block_pcs = block_loc + NBLK;
    int*   done      = (int*)(block_pcs + NBLK);

    hipLaunchKernelGGL(main_kernel, dim3(NBLK), dim3(TPB), 0, stream,
                       scores, boxes, gt_labels, gt_boxes, mask,
                       conf_neg, block_loc, block_pcs, done);
    hipLaunchKernelGGL(topk_kernel, dim3(NB), dim3(1024), 0, stream,
                       conf_neg, mask, pos_count, accv,
                       block_loc, block_pcs, done, out);
}

// Round 4
// 302.432 us; speedup vs baseline: 1.0046x; 1.0046x over previous
//
#include <hip/hip_runtime.h>
#include <math.h>

#define NB 64
#define NA 8732
#define NC 81
#define TOTAL (NB * NA)    /* 558848 */
#define APB 128            /* anchors per block */
#define TPB 512            /* threads per block: 4 threads per anchor */
#define NBLK (TOTAL / APB) /* 4366 */

// ws layout (no init kernel: every word read is stored in-iteration;
// 'done' is zeroed by main_kernel block 0 before topk runs):
//   float conf_neg[TOTAL]
//   int   pos_count[NB]    (written by topk_kernel)
//   float accv[NB]         (per-image neg-topk sum, written by topk_kernel)
//   float block_loc[NBLK]
//   float block_pcs[NBLK]
//   int   done             (last-topk-block detection counter)

// quad_perm butterfly all-reduce within each 4-lane group (full-rate VALU)
__device__ __forceinline__ float quadsum(float x) {
    x += __int_as_float(__builtin_amdgcn_update_dpp(
        0, __float_as_int(x), 0xB1, 0xF, 0xF, true));   // [1,0,3,2]
    x += __int_as_float(__builtin_amdgcn_update_dpp(
        0, __float_as_int(x), 0x4E, 0xF, 0xF, true));   // [2,3,0,1]
    return x;
}

// async global->LDS, 16B per lane. LDS dest is wave-uniform base + lane*16;
// our layout is exactly linear (dst[tid] = src[tid]) so this is valid.
__device__ __forceinline__ void gload_lds16(const float4* g, float4* l) {
    __builtin_amdgcn_global_load_lds(
        (const __attribute__((address_space(1))) unsigned int*)g,
        (__attribute__((address_space(3))) unsigned int*)l,
        16, 0, 0);
}

// Bulk-staged softmax CE. APB=128 / TPB=512: 41.4 KB LDS -> 3 blocks/CU
// (24 waves/CU). Round-3 showed APB=64 (more, smaller blocks) is ~19 us
// WORSE: per-block fixed overhead dominates over extra occupancy.
__global__ __launch_bounds__(TPB) void main_kernel(
    const float* __restrict__ scores, const float* __restrict__ boxes,
    const int* __restrict__ gt_labels, const float* __restrict__ gt_boxes,
    const int* __restrict__ mask, float* __restrict__ conf_neg,
    float* __restrict__ block_loc, float* __restrict__ block_pcs,
    int* __restrict__ done)
{
    __shared__ float lds[APB * NC];   // 41472 B
    __shared__ float wredl[8], wredp[8];
    const int tid  = threadIdx.x;
    const int lane = tid & 63;
    const int wid  = tid >> 6;        // 8 waves
    const int base = blockIdx.x * APB;

    if (blockIdx.x == 0 && tid == 0) *done = 0;   // for topk's last-block sync

    // ---- staging: 2592 float4 = 5*512 + 32, direct-to-LDS (no VGPR trip) ----
    const float4* __restrict__ src = (const float4*)(scores + (size_t)base * NC);
    float4* dst = (float4*)lds;
    gload_lds16(src + tid,        dst + tid);
    gload_lds16(src + tid +  512, dst + tid +  512);
    gload_lds16(src + tid + 1024, dst + tid + 1024);
    gload_lds16(src + tid + 1536, dst + tid + 1536);
    gload_lds16(src + tid + 2048, dst + tid + 2048);
    if (tid < 32) gload_lds16(src + tid + 2560, dst + tid + 2560);

    // ---- loc part (overlaps staging): threads 0..127 own one anchor ----
    float loc = 0.0f;
    if (tid < APB) {
        const int a = base + tid;
        if (mask[a]) {
            const float4 bx = *(const float4*)(boxes    + (size_t)a * 4);
            const float4 gb = *(const float4*)(gt_boxes + (size_t)a * 4);
            const float d0 = bx.x - gb.x, d1 = bx.y - gb.y;
            const float d2 = bx.z - gb.z, d3 = bx.w - gb.w;
            const float a0 = fabsf(d0), a1 = fabsf(d1), a2 = fabsf(d2), a3 = fabsf(d3);
            loc = (a0 < 1.f ? 0.5f * d0 * d0 : a0 - 0.5f)
                + (a1 < 1.f ? 0.5f * d1 * d1 : a1 - 0.5f)
                + (a2 < 1.f ? 0.5f * d2 * d2 : a2 - 0.5f)
                + (a3 < 1.f ? 0.5f * d3 * d3 : a3 - 0.5f);
        }
    }
    __syncthreads();                  // drains global_load_lds (vmcnt 0)

    // ---- CE: 4 threads per anchor, 20(+1) classes each ----
    const int al = tid >> 2;          // local anchor 0..127
    const int q  = tid & 3;
    const float* __restrict__ row = lds + al * NC;
    float e = 0.0f;
    #pragma unroll
    for (int j = 0; j < 20; ++j) e += __expf(row[q * 20 + j]);
    if (q == 3) e += __expf(row[80]);
    e = quadsum(e);                   // all 4 lanes hold sum(exp)

    float pcs = 0.0f;
    if (q == 0) {                     // leader: 16 lanes/wave, coalesced I/O
        const int a = base + al;
        const int lab = gt_labels[a];
        const float c = __logf(e) - row[lab];
        const int m = mask[a];
        conf_neg[a] = m ? 0.f : c;
        pcs = m ? c : 0.f;
    }

    #pragma unroll
    for (int o = 32; o; o >>= 1) {
        loc += __shfl_down(loc, o);
        pcs += __shfl_down(pcs, o);
    }
    if (lane == 0) { wredl[wid] = loc; wredp[wid] = pcs; }
    __syncthreads();
    if (tid == 0) {
        float sl = 0.f, sp = 0.f;
        #pragma unroll
        for (int w = 0; w < 8; ++w) { sl += wredl[w]; sp += wredp[w]; }
        block_loc[blockIdx.x] = sl;       // plain stores, no contention
        block_pcs[blockIdx.x] = sp;
    }
}

// One block per batch row. Computes k = 3*popcount(mask row) (fused into the
// staging loop), exact k-th-largest via radix-256 select on float bits, sum
// of top-k with tie handling. The LAST block to finish (device-scope counter)
// also performs the final global reduction and writes the outputs.
__global__ __launch_bounds__(1024) void topk_kernel(
    const float* __restrict__ conf_neg, const int* __restrict__ mask,
    int* __restrict__ pos_count, float* __restrict__ accv,
    const float* __restrict__ block_loc, const float* __restrict__ block_pcs,
    int* __restrict__ done, float* __restrict__ out)
{
    __shared__ unsigned sv[NA];                     // 34928 B
    __shared__ __align__(16) int whist[64][256];    // 65536 B, per-16-lane-group
    __shared__ int hist4[4][256];                   // 4096 B partial combine
    __shared__ int   redi[16];
    __shared__ float redf[16];
    __shared__ float rl[16], rp[16];
    __shared__ unsigned spfx;
    __shared__ int skr;
    __shared__ int sk;
    __shared__ int lastflag;
    const int tid  = threadIdx.x;
    const int lane = tid & 63;
    const int wid  = tid >> 6;
    const int hid  = tid >> 4;       // 64 sub-histograms
    const int b = blockIdx.x;
    const float* __restrict__ row  = conf_neg + (size_t)b * NA;
    const int*   __restrict__ mrow = mask     + (size_t)b * NA;

    // stage values + count positives in one pass
    int myc = 0;
    for (int i = tid; i < NA; i += 1024) {
        sv[i] = __float_as_uint(row[i]);
        myc += mrow[i];
    }
    #pragma unroll
    for (int o = 32; o; o >>= 1) myc += __shfl_down(myc, o);
    if (lane == 0) redi[wid] = myc;
    __syncthreads();
    if (tid == 0) {
        int p = 0;
        #pragma unroll
        for (int w = 0; w < 16; ++w) p += redi[w];
        pos_count[b] = p;
        int kk = 3 * p;
        if (kk > NA) kk = NA;
        sk = kk;
    }
    __syncthreads();
    const int k = sk;                // block-uniform

    if (k > 0) {
        unsigned prefix = 0u;
        int kr = k;
        for (int shift = 24; shift >= 0; shift -= 8) {
            // clear 64x256 ints with int4 stores: 4 per thread
            int4* w4 = (int4*)whist;
            const int4 z = make_int4(0, 0, 0, 0);
            w4[tid] = z; w4[tid + 1024] = z; w4[tid + 2048] = z; w4[tid + 3072] = z;
            __syncthreads();                                   // A

            const unsigned himask = (shift == 24) ? 0u : (0xFFFFFFFFu << (shift + 8));
            for (int i = tid; i < NA; i += 1024) {
                const unsigned v = sv[i];
                if ((v & himask) == prefix)
                    atomicAdd(&whist[hid][(v >> shift) & 255], 1);
            }
            __syncthreads();                                   // B

            // combine 64 copies -> hist4[4][256]
            {
                const int p = tid >> 8;        // 0..3
                const int bb = tid & 255;
                int s = 0;
                #pragma unroll
                for (int w = 0; w < 16; ++w) s += whist[(p << 4) + w][bb];
                hist4[p][bb] = s;
            }
            __syncthreads();                                   // C

            // wave 0: suffix-count over 256 bins + k-th bin select
            if (wid == 0) {
                int h0, h1, h2, h3;
                {
                    const int b0i = 4 * lane;
                    h0 = hist4[0][b0i]     + hist4[1][b0i]     + hist4[2][b0i]     + hist4[3][b0i];
                    h1 = hist4[0][b0i + 1] + hist4[1][b0i + 1] + hist4[2][b0i + 1] + hist4[3][b0i + 1];
                    h2 = hist4[0][b0i + 2] + hist4[1][b0i + 2] + hist4[2][b0i + 2] + hist4[3][b0i + 2];
                    h3 = hist4[0][b0i + 3] + hist4[1][b0i + 3] + hist4[2][b0i + 3] + hist4[3][b0i + 3];
                }
                const int s3 = h3, s2 = h2 + s3, s1 = h1 + s2, s0 = h0 + s1;
                int incl = s0;
                #pragma unroll
                for (int off = 1; off < 64; off <<= 1) {
                    const int v = __shfl_down(incl, off);
                    if (lane + off < 64) incl += v;
                }
                const int E = incl - s0;       // count in bins > 4*lane+3
                const int S0 = E + s0, S1 = E + s1, S2 = E + s2, S3 = E + s3;
                if (S0 >= kr && S1 < kr) { spfx = prefix | ((unsigned)(4 * lane)     << shift); skr = kr - S1; }
                else if (S1 >= kr && S2 < kr) { spfx = prefix | ((unsigned)(4 * lane + 1) << shift); skr = kr - S2; }
                else if (S2 >= kr && S3 < kr) { spfx = prefix | ((unsigned)(4 * lane + 2) << shift); skr = kr - S3; }
                else if (S3 >= kr && E  < kr) { spfx = prefix | ((unsigned)(4 * lane + 3) << shift); skr = kr - E;  }
            }
            __syncthreads();                                   // D (publish)
            prefix = spfx;
            kr = skr;
        }

        // prefix == bits of the k-th largest value T.
        // sum = sum(v > T) + (k - count(v > T)) * T   (exact tie handling)
        float s = 0.0f; int cg = 0;
        for (int i = tid; i < NA; i += 1024) {
            const unsigned u = sv[i];
            if (u > prefix) { s += __uint_as_float(u); cg++; }
        }
        #pragma unroll
        for (int o = 32; o; o >>= 1) { s += __shfl_down(s, o); cg += __shfl_down(cg, o); }
        if ((tid & 63) == 0) { redf[wid] = s; redi[wid] = cg; }
        __syncthreads();
        if (tid == 0) {
            float ts = 0.f; int tc = 0;
            #pragma unroll
            for (int w = 0; w < 16; ++w) { ts += redf[w]; tc += redi[w]; }
            ts += (float)(k - tc) * __uint_as_float(prefix);
            accv[b] = ts;
        }
    } else {
        if (tid == 0) accv[b] = 0.0f;
    }

    // ---- last-block-done: the final global reduction (replaces final_kernel)
    __threadfence();                              // release our stores
    if (tid == 0) lastflag = (atomicAdd(done, 1) == NB - 1);
    __syncthreads();
    if (!lastflag) return;
    __threadfence();                              // acquire others' stores

    float sl = 0.f, sp = 0.f;
    for (int i = tid; i < NBLK; i += 1024) { sl += block_loc[i]; sp += block_pcs[i]; }
    int   p2 = (tid < NB) ? pos_count[tid] : 0;   // wave 0 only
    float sa = (tid < NB) ? accv[tid]      : 0.f; // wave 0 only
    #pragma unroll
    for (int o = 32; o; o >>= 1) {
        sl += __shfl_down(sl, o);
        sp += __shfl_down(sp, o);
        p2 += __shfl_down(p2, o);
        sa += __shfl_down(sa, o);
    }
    if (lane == 0) { rl[wid] = sl; rp[wid] = sp; }
    __syncthreads();
    if (tid == 0) {
        float tl = 0.f, tp = 0.f;
        #pragma unroll
        for (int w = 0; w < 16; ++w) { tl += rl[w]; tp += rp[w]; }
        const float N = fmaxf(1.0f, (float)p2);   // p2, sa live in wave-0 lane-0
        const float loc  = tl / N;
        const float conf = (tp + sa) / N;
        out[0] = loc + conf;
        out[1] = loc;
        out[2] = conf;
    }
}

extern "C" void kernel_launch(void* const* d_in, const int* in_sizes, int n_in,
                              void* d_out, int out_size, void* d_ws, size_t ws_size,
                              hipStream_t stream) {
    const float* scores    = (const float*)d_in[0];
    const float* boxes     = (const float*)d_in[1];
    const int*   gt_labels = (const int*)d_in[2];
    const float* gt_boxes  = (const float*)d_in[3];
    const int*   mask      = (const int*)d_in[4];
    float* out = (float*)d_out;

    float* conf_neg  = (float*)d_ws;
    int*   pos_count = (int*)(conf_neg + TOTAL);
    float* accv      = (float*)(pos_count + NB);
    float* block_loc = accv + NB;
    float* block_pcs = block_loc + NBLK;
    int*   done      = (int*)(block_pcs + NBLK);

    hipLaunchKernelGGL(main_kernel, dim3(NBLK), dim3(TPB), 0, stream,
                       scores, boxes, gt_labels, gt_boxes, mask,
                       conf_neg, block_loc, block_pcs, done);
    hipLaunchKernelGGL(topk_kernel, dim3(NB), dim3(1024), 0, stream,
                       conf_neg, mask, pos_count, accv,
                       block_loc, block_pcs, done, out);
}

// Round 5
// 282.998 us; speedup vs baseline: 1.0736x; 1.0687x over previous
//
#include <hip/hip_runtime.h>
#include <math.h>

#define NB 64
#define NA 8732
#define NC 81
#define TOTAL (NB * NA)    /* 558848 */
#define APB 128            /* anchors per block */
#define TPB 512            /* threads per block: 4 threads per anchor */
#define NBLK (TOTAL / APB) /* 4366 */

// ws layout (no init kernel: every word read is stored in-iteration):
//   float conf_neg[TOTAL]
//   int   pos_count[NB]    (written by topk_kernel)
//   float accv[NB]         (per-image neg-topk sum, written by topk_kernel)
//   float block_loc[NBLK]
//   float block_pcs[NBLK]
//
// Session A/B findings baked into this structure:
//  - R3: APB 64 (7 blocks/CU) vs 128 (3 blocks/CU): ~neutral. Per-block
//    fixed overhead offsets the occupancy gain; staging is HBM-BW-bound
//    either way. Keep 128.
//  - R4: merging final_kernel into topk via last-block-done + 2x
//    __threadfence() costs +17 us: device-scope fences force L2
//    writeback/invalidate (per-XCD L2s non-coherent; L2 is fully dirty
//    from the harness poison fill). A separate ~5 us launch is cheaper
//    than 128 device fences. Keep 3 kernels, zero device fences.

// quad_perm butterfly all-reduce within each 4-lane group (full-rate VALU)
__device__ __forceinline__ float quadsum(float x) {
    x += __int_as_float(__builtin_amdgcn_update_dpp(
        0, __float_as_int(x), 0xB1, 0xF, 0xF, true));   // [1,0,3,2]
    x += __int_as_float(__builtin_amdgcn_update_dpp(
        0, __float_as_int(x), 0x4E, 0xF, 0xF, true));   // [2,3,0,1]
    return x;
}

// async global->LDS, 16B per lane. LDS dest is wave-uniform base + lane*16;
// our layout is exactly linear (dst[tid] = src[tid]) so this is valid.
__device__ __forceinline__ void gload_lds16(const float4* g, float4* l) {
    __builtin_amdgcn_global_load_lds(
        (const __attribute__((address_space(1))) unsigned int*)g,
        (__attribute__((address_space(3))) unsigned int*)l,
        16, 0, 0);
}

// Bulk-staged softmax CE. Zero atomics of any kind: per-block partials go
// out via plain stores; pos_count is computed in topk_kernel from mask.
// Staging at 41.4 KB/block x 4366 blocks = 181 MB == the HBM floor; with 3
// resident blocks/CU the per-block vmcnt(0) drain pipelines across blocks.
__global__ __launch_bounds__(TPB) void main_kernel(
    const float* __restrict__ scores, const float* __restrict__ boxes,
    const int* __restrict__ gt_labels, const float* __restrict__ gt_boxes,
    const int* __restrict__ mask, float* __restrict__ conf_neg,
    float* __restrict__ block_loc, float* __restrict__ block_pcs)
{
    __shared__ float lds[APB * NC];   // 41472 B -> 3 blocks/CU
    __shared__ float wredl[8], wredp[8];
    const int tid  = threadIdx.x;
    const int lane = tid & 63;
    const int wid  = tid >> 6;        // 8 waves
    const int base = blockIdx.x * APB;

    // ---- staging: 2592 float4 = 5*512 + 32, direct-to-LDS (no VGPR trip) ----
    const float4* __restrict__ src = (const float4*)(scores + (size_t)base * NC);
    float4* dst = (float4*)lds;
    gload_lds16(src + tid,        dst + tid);
    gload_lds16(src + tid +  512, dst + tid +  512);
    gload_lds16(src + tid + 1024, dst + tid + 1024);
    gload_lds16(src + tid + 1536, dst + tid + 1536);
    gload_lds16(src + tid + 2048, dst + tid + 2048);
    if (tid < 32) gload_lds16(src + tid + 2560, dst + tid + 2560);

    // ---- loc part (overlaps staging): threads 0..127 own one anchor ----
    float loc = 0.0f;
    if (tid < APB) {
        const int a = base + tid;
        if (mask[a]) {
            const float4 bx = *(const float4*)(boxes    + (size_t)a * 4);
            const float4 gb = *(const float4*)(gt_boxes + (size_t)a * 4);
            const float d0 = bx.x - gb.x, d1 = bx.y - gb.y;
            const float d2 = bx.z - gb.z, d3 = bx.w - gb.w;
            const float a0 = fabsf(d0), a1 = fabsf(d1), a2 = fabsf(d2), a3 = fabsf(d3);
            loc = (a0 < 1.f ? 0.5f * d0 * d0 : a0 - 0.5f)
                + (a1 < 1.f ? 0.5f * d1 * d1 : a1 - 0.5f)
                + (a2 < 1.f ? 0.5f * d2 * d2 : a2 - 0.5f)
                + (a3 < 1.f ? 0.5f * d3 * d3 : a3 - 0.5f);
        }
    }
    __syncthreads();                  // drains global_load_lds (vmcnt 0)

    // ---- CE: 4 threads per anchor, 20(+1) classes each ----
    const int al = tid >> 2;          // local anchor 0..127
    const int q  = tid & 3;
    const float* __restrict__ row = lds + al * NC;
    float e = 0.0f;
    #pragma unroll
    for (int j = 0; j < 20; ++j) e += __expf(row[q * 20 + j]);
    if (q == 3) e += __expf(row[80]);
    e = quadsum(e);                   // all 4 lanes hold sum(exp)

    float pcs = 0.0f;
    if (q == 0) {                     // leader: 16 lanes/wave, coalesced I/O
        const int a = base + al;
        const int lab = gt_labels[a];
        const float c = __logf(e) - row[lab];
        const int m = mask[a];
        conf_neg[a] = m ? 0.f : c;
        pcs = m ? c : 0.f;
    }

    #pragma unroll
    for (int o = 32; o; o >>= 1) {
        loc += __shfl_down(loc, o);
        pcs += __shfl_down(pcs, o);
    }
    if (lane == 0) { wredl[wid] = loc; wredp[wid] = pcs; }
    __syncthreads();
    if (tid == 0) {
        float sl = 0.f, sp = 0.f;
        #pragma unroll
        for (int w = 0; w < 8; ++w) { sl += wredl[w]; sp += wredp[w]; }
        block_loc[blockIdx.x] = sl;       // plain stores, no contention
        block_pcs[blockIdx.x] = sp;
    }
}

// One block per batch row. Computes k = 3*popcount(mask row) itself (fused
// into the staging loop), then exact k-th-largest via radix-256 select
// (4 passes) on float bit patterns, then sum of top-k with tie handling.
// Results out via plain stores (pos_count[b], accv[b]) -- no init required.
// Histogram uses 64 sub-histograms keyed by tid>>4: CE values concentrate
// in [2,8) (top byte 0x40), so fewer copies = deep same-address LDS-atomic
// serialization (R0 lesson).
__global__ __launch_bounds__(1024) void topk_kernel(
    const float* __restrict__ conf_neg, const int* __restrict__ mask,
    int* __restrict__ pos_count, float* __restrict__ accv)
{
    __shared__ unsigned sv[NA];                     // 34928 B
    __shared__ __align__(16) int whist[64][256];    // 65536 B, per-16-lane-group
    __shared__ int hist4[4][256];                   // 4096 B partial combine
    __shared__ int   redi[16];
    __shared__ float redf[16];
    __shared__ unsigned spfx;
    __shared__ int skr;
    __shared__ int sk;
    const int tid  = threadIdx.x;
    const int lane = tid & 63;
    const int wid  = tid >> 6;
    const int hid  = tid >> 4;       // 64 sub-histograms
    const int b = blockIdx.x;
    const float* __restrict__ row  = conf_neg + (size_t)b * NA;
    const int*   __restrict__ mrow = mask     + (size_t)b * NA;

    // stage values + count positives in one pass
    int myc = 0;
    for (int i = tid; i < NA; i += 1024) {
        sv[i] = __float_as_uint(row[i]);
        myc += mrow[i];
    }
    #pragma unroll
    for (int o = 32; o; o >>= 1) myc += __shfl_down(myc, o);
    if (lane == 0) redi[wid] = myc;
    __syncthreads();
    if (tid == 0) {
        int p = 0;
        #pragma unroll
        for (int w = 0; w < 16; ++w) p += redi[w];
        pos_count[b] = p;
        int kk = 3 * p;
        if (kk > NA) kk = NA;
        sk = kk;
    }
    __syncthreads();
    int k = sk;
    if (k <= 0) {                    // uniform per block: safe early-out
        if (tid == 0) accv[b] = 0.0f;
        return;
    }

    unsigned prefix = 0u;
    int kr = k;
    for (int shift = 24; shift >= 0; shift -= 8) {
        // clear 64x256 ints with int4 stores: 4 per thread
        int4* w4 = (int4*)whist;
        const int4 z = make_int4(0, 0, 0, 0);
        w4[tid] = z; w4[tid + 1024] = z; w4[tid + 2048] = z; w4[tid + 3072] = z;
        __syncthreads();                                   // A

        const unsigned himask = (shift == 24) ? 0u : (0xFFFFFFFFu << (shift + 8));
        for (int i = tid; i < NA; i += 1024) {
            const unsigned v = sv[i];
            if ((v & himask) == prefix)
                atomicAdd(&whist[hid][(v >> shift) & 255], 1);
        }
        __syncthreads();                                   // B

        // combine 64 copies -> hist4[4][256]: thread (p, bin) sums 16 copies
        {
            const int p = tid >> 8;        // 0..3
            const int bb = tid & 255;
            int s = 0;
            #pragma unroll
            for (int w = 0; w < 16; ++w) s += whist[(p << 4) + w][bb];
            hist4[p][bb] = s;
        }
        __syncthreads();                                   // C

        // wave 0: suffix-count over 256 bins + k-th bin select, no barriers
        if (wid == 0) {
            int h0, h1, h2, h3;
            {
                const int b0i = 4 * lane;
                h0 = hist4[0][b0i]     + hist4[1][b0i]     + hist4[2][b0i]     + hist4[3][b0i];
                h1 = hist4[0][b0i + 1] + hist4[1][b0i + 1] + hist4[2][b0i + 1] + hist4[3][b0i + 1];
                h2 = hist4[0][b0i + 2] + hist4[1][b0i + 2] + hist4[2][b0i + 2] + hist4[3][b0i + 2];
                h3 = hist4[0][b0i + 3] + hist4[1][b0i + 3] + hist4[2][b0i + 3] + hist4[3][b0i + 3];
            }
            // per-lane suffix sums over its 4 bins
            const int s3 = h3, s2 = h2 + s3, s1 = h1 + s2, s0 = h0 + s1;
            // inclusive suffix sum of per-lane totals across the wave
            int incl = s0;
            #pragma unroll
            for (int off = 1; off < 64; off <<= 1) {
                const int v = __shfl_down(incl, off);
                if (lane + off < 64) incl += v;
            }
            const int E = incl - s0;       // count of values in bins > 4*lane+3
            const int S0 = E + s0, S1 = E + s1, S2 = E + s2, S3 = E + s3;
            // exactly one (lane, j) satisfies S_j >= kr > S_{j+1}
            if (S0 >= kr && S1 < kr) { spfx = prefix | ((unsigned)(4 * lane)     << shift); skr = kr - S1; }
            else if (S1 >= kr && S2 < kr) { spfx = prefix | ((unsigned)(4 * lane + 1) << shift); skr = kr - S2; }
            else if (S2 >= kr && S3 < kr) { spfx = prefix | ((unsigned)(4 * lane + 2) << shift); skr = kr - S3; }
            else if (S3 >= kr && E  < kr) { spfx = prefix | ((unsigned)(4 * lane + 3) << shift); skr = kr - E;  }
        }
        __syncthreads();                                   // D (publish)
        prefix = spfx;
        kr = skr;
        // safe: next write to spfx/skr happens only after barrier C of the
        // next pass, and every thread reads them before barrier A.
    }

    // prefix == bits of the k-th largest value T.
    // sum = sum(v > T) + (k - count(v > T)) * T   (exact tie handling)
    float s = 0.0f; int cg = 0;
    for (int i = tid; i < NA; i += 1024) {
        const unsigned u = sv[i];
        if (u > prefix) { s += __uint_as_float(u); cg++; }
    }
    #pragma unroll
    for (int o = 32; o; o >>= 1) { s += __shfl_down(s, o); cg += __shfl_down(cg, o); }
    if ((tid & 63) == 0) { redf[wid] = s; redi[wid] = cg; }
    __syncthreads();
    if (tid == 0) {
        float ts = 0.f; int tc = 0;
        #pragma unroll
        for (int w = 0; w < 16; ++w) { ts += redf[w]; tc += redi[w]; }
        ts += (float)(k - tc) * __uint_as_float(prefix);
        accv[b] = ts;                 // plain store, summed in final_kernel
    }
}

// Single block: reduce the 4366 per-block partials + 64 pos counts + 64
// per-image topk sums, emit outputs. Kept as a separate launch on purpose:
// fence-based fusion into topk measured +17 us (R4).
__global__ __launch_bounds__(1024) void final_kernel(
    const float* __restrict__ block_loc, const float* __restrict__ block_pcs,
    const int* __restrict__ pos_count, const float* __restrict__ accv,
    float* __restrict__ out)
{
    __shared__ float rl[16], rp[16];
    const int tid = threadIdx.x;
    const int wid = tid >> 6;
    float sl = 0.f, sp = 0.f;
    for (int i = tid; i < NBLK; i += 1024) { sl += block_loc[i]; sp += block_pcs[i]; }
    int   p  = (tid < NB) ? pos_count[tid] : 0;     // wave 0 only
    float sa = (tid < NB) ? accv[tid]      : 0.f;   // wave 0 only
    #pragma unroll
    for (int o = 32; o; o >>= 1) {
        sl += __shfl_down(sl, o);
        sp += __shfl_down(sp, o);
        p  += __shfl_down(p, o);
        sa += __shfl_down(sa, o);
    }
    if ((tid & 63) == 0) { rl[wid] = sl; rp[wid] = sp; }
    __syncthreads();
    if (tid == 0) {
        float tl = 0.f, tp = 0.f;
        #pragma unroll
        for (int w = 0; w < 16; ++w) { tl += rl[w]; tp += rp[w]; }
        const float N = fmaxf(1.0f, (float)p);   // p, sa live in wave-0 lane-0
        const float loc  = tl / N;
        const float conf = (tp + sa) / N;
        out[0] = loc + conf;
        out[1] = loc;
        out[2] = conf;
    }
}

extern "C" void kernel_launch(void* const* d_in, const int* in_sizes, int n_in,
                              void* d_out, int out_size, void* d_ws, size_t ws_size,
                              hipStream_t stream) {
    const float* scores    = (const float*)d_in[0];
    const float* boxes     = (const float*)d_in[1];
    const int*   gt_labels = (const int*)d_in[2];
    const float* gt_boxes  = (const float*)d_in[3];
    const int*   mask      = (const int*)d_in[4];
    float* out = (float*)d_out;

    float* conf_neg  = (float*)d_ws;
    int*   pos_count = (int*)(conf_neg + TOTAL);
    float* accv      = (float*)(pos_count + NB);
    float* block_loc = accv + NB;
    float* block_pcs = block_loc + NBLK;

    hipLaunchKernelGGL(main_kernel, dim3(NBLK), dim3(TPB), 0, stream,
                       scores, boxes, gt_labels, gt_boxes, mask,
                       conf_neg, block_loc, block_pcs);
    hipLaunchKernelGGL(topk_kernel, dim3(NB), dim3(1024), 0, stream,
                       conf_neg, mask, pos_count, accv);
    hipLaunchKernelGGL(final_kernel, dim3(1), dim3(1024), 0, stream,
                       block_loc, block_pcs, pos_count, accv, out);
}